// Round 4
// baseline (226.861 us; speedup 1.0000x reference)
//
#include <hip/hip_runtime.h>

typedef _Float16 half4_t __attribute__((ext_vector_type(4)));
typedef _Float16 half8_t __attribute__((ext_vector_type(8)));
typedef float f32x4 __attribute__((ext_vector_type(4)));

constexpr int NX = 256, NU = 32, NY = 32, BATCH = 16, T = 8192;
constexpr int NC = 64, L = 128;       // 64 chunks of 128 steps
constexpr int SUBT = 32, NSUB = L / SUBT;
constexpr int KW = NX + NU;           // 288 projection K: [z | u]
constexpr int VP = 40;                // V'^T pitch (halves)
constexpr int ZP = 264;               // zt pitch (halves)
constexpr int POOLSZ = NX * VP;       // 10240 halves >= 32*ZP = 8448
constexpr int WP = 296;               // W row pitch in LDS (halves), 592B: bank offset 20/row

// ---------- pre: Bzh=(Q^T Bm) f16, Wh=[CQ|D] f16, z0=x0 Q f32 ; split-K x4 ----------
__global__ __launch_bounds__(256) void k_pre(
    const float* __restrict__ x0, const float* __restrict__ Q,
    const float* __restrict__ Bm, const float* __restrict__ C,
    const float* __restrict__ D,
    _Float16* __restrict__ Bzh, _Float16* __restrict__ Wh, float* __restrict__ z0)
{
    int o = blockIdx.x * 64 + (threadIdx.x >> 2);
    int p = threadIdx.x & 3;
    if (o >= 20480) {                                   // D copy
        if (p == 0) {
            int g = o - 20480, iy = g >> 5, j = g & 31;
            Wh[iy * KW + NX + j] = (_Float16)D[iy * NU + j];
        }
        return;
    }
    float s = 0.f;
    int k0 = p * 64;
    if (o < 8192) {                                     // Bzh[n][j] = sum_k Q[k][n] Bm[k][j]
        int n = o >> 5, j = o & 31;
        for (int k = k0; k < k0 + 64; ++k) s = fmaf(Q[k * NX + n], Bm[k * NU + j], s);
    } else if (o < 16384) {                             // CQ[iy][nn]
        int g = o - 8192; int iy = g >> 8, nn = g & 255;
        for (int k = k0; k < k0 + 64; ++k) s = fmaf(C[iy * NX + k], Q[k * NX + nn], s);
    } else {                                            // z0[b][nn]
        int g = o - 16384; int b = g >> 8, nn = g & 255;
        for (int k = k0; k < k0 + 64; ++k) s = fmaf(x0[b * NX + k], Q[k * NX + nn], s);
    }
    s += __shfl_xor(s, 1);
    s += __shfl_xor(s, 2);
    if (p == 0) {
        if (o < 8192) {
            Bzh[o] = (_Float16)s;
        } else if (o < 16384) {
            int g = o - 8192; int iy = g >> 8, nn = g & 255;
            Wh[iy * KW + nn] = (_Float16)s;
        } else {
            z0[o - 16384] = s;
        }
    }
}

// ---------- fused main: pass A (aggregate) -> publish -> prefix -> pass B (y) ----------
__global__ __launch_bounds__(256) void k_main(
    const float* __restrict__ u, const float* __restrict__ lam,
    const _Float16* __restrict__ Bzh, const _Float16* __restrict__ Wh,
    const float* __restrict__ z0, float* Sagg, int* flags,
    float* __restrict__ y)
{
    __shared__ __align__(16) _Float16 ut[NSUB][SUBT][32];   // 8 KB, persistent u chunk
    __shared__ __align__(16) _Float16 pool[POOLSZ];         // 20.5 KB: V'^T then zt
    __shared__ __align__(16) _Float16 wsh[NY][WP];          // 18.9 KB: [Cz|D] padded
    __shared__ float pvec[NX];                              // 1 KB

    const int bx = blockIdx.x, b = bx >> 6, c = bx & 63, tid = threadIdx.x;
    const int w = tid >> 6, lane = tid & 63, m16 = lane & 15, quad = lane >> 4;
    const int tw = w & 1, yw = w >> 1;
    const int rot = (m16 & 3) * 8;

    // stage W = [Cz|D] into padded LDS rows (consumed in pass B)
    {
        int r = tid >> 3;
        for (int j = tid & 7; j < KW / 8; j += 8)
            *(half8_t*)&wsh[r][j * 8] = *(const half8_t*)&Wh[r * KW + j * 8];
    }

    half8_t bfrag[4];
    #pragma unroll
    for (int i = 0; i < 4; ++i)
        bfrag[i] = *(const half8_t*)&Bzh[((4 * w + i) * 16 + m16) * NU + quad * 8];

    const float* ug = u + ((size_t)(b * T) + (size_t)c * L) * NU;

    // ---- pass A: stage u, v-MFMA, weighted reduction -> S_c ----
    float acc[4];
    {
        float wr[4][4], wt16[4], l32[4];
        #pragma unroll
        for (int i = 0; i < 4; ++i) {
            float la = lam[(4 * w + i) * 16 + m16];
            float p2 = la * la, p4 = p2 * p2, p8 = p4 * p4, p16 = p8 * p8;
            float iv = 1.0f / la;
            float iv4 = (iv * iv) * (iv * iv);
            float pq = 1.0f;
            if (quad & 1) pq *= iv4;
            if (quad & 2) pq *= iv4 * iv4;
            float w0 = (p16 * p8 * p4 * p2 * la) * pq;      // lam^(31-4q)
            wr[i][0] = w0;
            wr[i][1] = w0 * iv;
            wr[i][2] = wr[i][1] * iv;
            wr[i][3] = wr[i][2] * iv;
            wt16[i] = 1.0f / p16;
            l32[i] = p16 * p16;
            acc[i] = 0.f;
        }
        for (int sub = 0; sub < NSUB; ++sub) {
            {   // stage u tile f16, swizzled: col' = (col + (t&3)*8) & 31
                float4 uu = *(const float4*)(ug + (size_t)sub * SUBT * NU + tid * 4);
                int tr = tid >> 3, cb = ((tid & 7) * 4 + (tr & 3) * 8) & 31;
                half4_t h; h.x = (_Float16)uu.x; h.y = (_Float16)uu.y;
                h.z = (_Float16)uu.z; h.w = (_Float16)uu.w;
                *(half4_t*)&ut[sub][tr][cb] = h;
            }
            __syncthreads();
            half8_t af0 = *(const half8_t*)&ut[sub][m16][(quad * 8 + rot) & 31];
            half8_t af1 = *(const half8_t*)&ut[sub][16 + m16][(quad * 8 + rot) & 31];
            #pragma unroll
            for (int i = 0; i < 4; ++i) {
                f32x4 z4 = {0.f, 0.f, 0.f, 0.f};
                f32x4 v0 = __builtin_amdgcn_mfma_f32_16x16x32_f16(af0, bfrag[i], z4, 0, 0, 0);
                f32x4 v1 = __builtin_amdgcn_mfma_f32_16x16x32_f16(af1, bfrag[i], z4, 0, 0, 0);
                float s0 = wr[i][0] * v0[0] + wr[i][1] * v0[1] + wr[i][2] * v0[2] + wr[i][3] * v0[3];
                float s1 = wr[i][0] * v1[0] + wr[i][1] * v1[1] + wr[i][2] * v1[2] + wr[i][3] * v1[3];
                acc[i] = fmaf(l32[i], acc[i], fmaf(wt16[i], s1, s0));
            }
        }
    }
    // reduce + publish aggregate (agent-scope so other XCDs see it)
    #pragma unroll
    for (int i = 0; i < 4; ++i) {
        acc[i] += __shfl_xor(acc[i], 16);
        acc[i] += __shfl_xor(acc[i], 32);
    }
    {
        float sout = quad == 0 ? acc[0] : quad == 1 ? acc[1] : quad == 2 ? acc[2] : acc[3];
        int nout = (4 * w + quad) * 16 + m16;
        __hip_atomic_store(&Sagg[(size_t)bx * NX + nout], sout,
                           __ATOMIC_RELAXED, __HIP_MEMORY_SCOPE_AGENT);
        __threadfence();
        __syncthreads();
        if (tid == 0)
            __hip_atomic_store(&flags[bx], 1, __ATOMIC_RELEASE, __HIP_MEMORY_SCOPE_AGENT);
    }

    // ---- prefix: p = sum_k lamL^k S_{c-1-k} + lamL^c z0 (pipelined loads) ----
    if (c > 0) {
        if (tid < c) {
            int* fp = flags + b * NC + tid;
            while (__hip_atomic_load(fp, __ATOMIC_ACQUIRE, __HIP_MEMORY_SCOPE_AGENT) != 1)
                __builtin_amdgcn_s_sleep(2);
        }
        __syncthreads();
        float la = lam[tid], lamL = la;
        #pragma unroll
        for (int i = 0; i < 7; ++i) lamL *= lamL;           // lam^128
        float p = 0.f, wgt = 1.f;
        float* Sb = Sagg + (size_t)(b * NC) * NX;
        for (int cc = c - 1; cc >= 0; --cc) {
            float sv = __hip_atomic_load(&Sb[(size_t)cc * NX + tid],
                                         __ATOMIC_RELAXED, __HIP_MEMORY_SCOPE_AGENT);
            p = fmaf(wgt, sv, p);
            wgt *= lamL;
        }
        pvec[tid] = fmaf(wgt, z0[b * NX + tid], p);
    } else {
        pvec[tid] = z0[b * NX + tid];
    }
    __syncthreads();

    // ---- pass B: v-MFMA -> Tri-MFMA scan -> projection MFMA -> y ----
    float lamn[4], inv1[4], iq[4], i16p[4], fq[4], f16p[4], l32b[4], p[4];
    #pragma unroll
    for (int i = 0; i < 4; ++i) {
        int ni = (4 * w + i) * 16 + m16;
        float la = lam[ni];
        lamn[i] = la;
        float p2 = la * la, p4 = p2 * p2, p8 = p4 * p4, p16 = p8 * p8;
        float iv = 1.0f / la;
        inv1[i] = iv;
        float iv4 = (iv * iv) * (iv * iv);
        float pqi = 1.0f, pqf = 1.0f;
        if (quad & 1) { pqi *= iv4; pqf *= p4; }
        if (quad & 2) { pqi *= iv4 * iv4; pqf *= p8; }
        iq[i] = iv * pqi;                               // lam^-(1+4q)
        fq[i] = pqf;                                    // lam^(4q)
        i16p[i] = 1.0f / p16;
        f16p[i] = p16;
        l32b[i] = p16 * p16;
        p[i] = pvec[ni];
    }
    half8_t triA[2];                                    // Tri[t][s] = (s < t)
    #pragma unroll
    for (int tt = 0; tt < 2; ++tt) {
        #pragma unroll
        for (int j = 0; j < 8; ++j)
            triA[tt][j] = (_Float16)((quad * 8 + j < tt * 16 + m16) ? 1.f : 0.f);
    }
    float* yg = y + ((size_t)(b * T) + (size_t)c * L) * NY;

    for (int sub = 0; sub < NSUB; ++sub) {
        __syncthreads();                                 // Ba: prior proj reads done
        half8_t af0 = *(const half8_t*)&ut[sub][m16][(quad * 8 + rot) & 31];
        half8_t af1 = *(const half8_t*)&ut[sub][16 + m16][(quad * 8 + rot) & 31];
        float partial[4];
        #pragma unroll
        for (int i = 0; i < 4; ++i) {
            int ni = (4 * w + i) * 16 + m16;
            f32x4 z4 = {0.f, 0.f, 0.f, 0.f};
            f32x4 v0 = __builtin_amdgcn_mfma_f32_16x16x32_f16(af0, bfrag[i], z4, 0, 0, 0);
            f32x4 v1 = __builtin_amdgcn_mfma_f32_16x16x32_f16(af1, bfrag[i], z4, 0, 0, 0);
            float ps = 0.f;
            float sc = iq[i];
            half4_t h0, h1;
            #pragma unroll
            for (int r = 0; r < 4; ++r) {
                float a0 = v0[r] * sc;
                float a1 = v1[r] * (sc * i16p[i]);
                ps += a0 + a1;
                h0[r] = (_Float16)a0;
                h1[r] = (_Float16)a1;
                sc *= inv1[i];
            }
            partial[i] = ps;
            *(half4_t*)&pool[ni * VP + quad * 4] = h0;
            *(half4_t*)&pool[ni * VP + 16 + quad * 4] = h1;
        }
        __syncthreads();                                 // Bb
        f32x4 zp0[4], zp1[4];
        #pragma unroll
        for (int i = 0; i < 4; ++i) {
            int ni = (4 * w + i) * 16 + m16;
            half8_t bV = *(const half8_t*)&pool[ni * VP + quad * 8];
            f32x4 z4 = {0.f, 0.f, 0.f, 0.f};
            zp0[i] = __builtin_amdgcn_mfma_f32_16x16x32_f16(triA[0], bV, z4, 0, 0, 0);
            zp1[i] = __builtin_amdgcn_mfma_f32_16x16x32_f16(triA[1], bV, z4, 0, 0, 0);
        }
        __syncthreads();                                 // Bc (pool: V'^T -> zt)
        #pragma unroll
        for (int i = 0; i < 4; ++i) {
            int ni = (4 * w + i) * 16 + m16;
            float f = fq[i];
            #pragma unroll
            for (int r = 0; r < 4; ++r) {
                float zv0 = f * (p[i] + zp0[i][r]);
                float zv1 = (f * f16p[i]) * (p[i] + zp1[i][r]);
                pool[(quad * 4 + r) * ZP + ni] = (_Float16)zv0;
                pool[(16 + quad * 4 + r) * ZP + ni] = (_Float16)zv1;
                f *= lamn[i];
            }
        }
        #pragma unroll
        for (int i = 0; i < 4; ++i) {
            float ps = partial[i];
            ps += __shfl_xor(ps, 16);
            ps += __shfl_xor(ps, 32);
            p[i] = l32b[i] * (p[i] + ps);
        }
        __syncthreads();                                 // Bd
        f32x4 acc2 = {0.f, 0.f, 0.f, 0.f};
        #pragma unroll
        for (int kk = 0; kk < 8; ++kk) {
            half8_t az = *(const half8_t*)&pool[(tw * 16 + m16) * ZP + kk * 32 + quad * 8];
            half8_t bw = *(const half8_t*)&wsh[yw * 16 + m16][kk * 32 + quad * 8];
            acc2 = __builtin_amdgcn_mfma_f32_16x16x32_f16(az, bw, acc2, 0, 0, 0);
        }
        {
            half8_t au = *(const half8_t*)&ut[sub][tw * 16 + m16][(quad * 8 + rot) & 31];
            half8_t bw = *(const half8_t*)&wsh[yw * 16 + m16][NX + quad * 8];
            acc2 = __builtin_amdgcn_mfma_f32_16x16x32_f16(au, bw, acc2, 0, 0, 0);
        }
        #pragma unroll
        for (int r = 0; r < 4; ++r)
            yg[(size_t)(sub * SUBT + tw * 16 + quad * 4 + r) * NY + yw * 16 + m16] = acc2[r];
    }
}

extern "C" void kernel_launch(void* const* d_in, const int* in_sizes, int n_in,
                              void* d_out, int out_size, void* d_ws, size_t ws_size,
                              hipStream_t stream) {
    (void)in_sizes; (void)n_in; (void)out_size; (void)ws_size;
    const float* x0  = (const float*)d_in[0];
    const float* u   = (const float*)d_in[1];
    const float* Q   = (const float*)d_in[2];
    const float* lam = (const float*)d_in[3];
    const float* Bm  = (const float*)d_in[4];
    const float* C   = (const float*)d_in[5];
    const float* D   = (const float*)d_in[6];
    float* y = (float*)d_out;

    char* ws = (char*)d_ws;
    _Float16* Bzh   = (_Float16*)(ws);                  // 16384 B
    _Float16* Wh    = (_Float16*)(ws + 16384);          // 18432 B
    float*    z0    = (float*)(ws + 34816);             // 16384 B
    float*    Sagg  = (float*)(ws + 51200);             // 1 MB
    int*      flags = (int*)(ws + 51200 + 1048576);     // 4 KB (0xAA poison != 1 ✓)

    k_pre <<<336, 256, 0, stream>>>(x0, Q, Bm, C, D, Bzh, Wh, z0);
    k_main<<<BATCH * NC, 256, 0, stream>>>(u, lam, Bzh, Wh, z0, Sagg, flags, y);
}

// Round 5
// 129.893 us; speedup vs baseline: 1.7465x; 1.7465x over previous
//
#include <hip/hip_runtime.h>

typedef _Float16 half4_t __attribute__((ext_vector_type(4)));
typedef _Float16 half8_t __attribute__((ext_vector_type(8)));
typedef float f32x4 __attribute__((ext_vector_type(4)));

constexpr int NX = 256, NU = 32, NY = 32, BATCH = 16, T = 8192;
constexpr int NC = 64, L = 128;       // 64 chunks of 128 steps
constexpr int SUBT = 32, NSUB = L / SUBT;
constexpr int KW = NX + NU;           // 288 projection K: [z | u]
constexpr int VP = 40;                // V'^T pitch (halves)
constexpr int ZP = 264;               // zt pitch (halves)
constexpr int POOLSZ = NX * VP;       // 10240 halves >= 32*ZP = 8448

// ---------- pre: Bzh=(Q^T Bm) f16, Wh=[CQ|D] f16, z0=x0 Q f32 ; split-K x4 ----------
__global__ __launch_bounds__(256) void k_pre(
    const float* __restrict__ x0, const float* __restrict__ Q,
    const float* __restrict__ Bm, const float* __restrict__ C,
    const float* __restrict__ D,
    _Float16* __restrict__ Bzh, _Float16* __restrict__ Wh, float* __restrict__ z0)
{
    int o = blockIdx.x * 64 + (threadIdx.x >> 2);
    int p = threadIdx.x & 3;
    if (o >= 20480) {                                   // D copy
        if (p == 0) {
            int g = o - 20480, iy = g >> 5, j = g & 31;
            Wh[iy * KW + NX + j] = (_Float16)D[iy * NU + j];
        }
        return;
    }
    float s = 0.f;
    int k0 = p * 64;
    if (o < 8192) {                                     // Bzh[n][j] = sum_k Q[k][n] Bm[k][j]
        int n = o >> 5, j = o & 31;
        for (int k = k0; k < k0 + 64; ++k) s = fmaf(Q[k * NX + n], Bm[k * NU + j], s);
    } else if (o < 16384) {                             // CQ[iy][nn]
        int g = o - 8192; int iy = g >> 8, nn = g & 255;
        for (int k = k0; k < k0 + 64; ++k) s = fmaf(C[iy * NX + k], Q[k * NX + nn], s);
    } else {                                            // z0[b][nn]
        int g = o - 16384; int b = g >> 8, nn = g & 255;
        for (int k = k0; k < k0 + 64; ++k) s = fmaf(x0[b * NX + k], Q[k * NX + nn], s);
    }
    s += __shfl_xor(s, 1);
    s += __shfl_xor(s, 2);
    if (p == 0) {
        if (o < 8192) {
            Bzh[o] = (_Float16)s;
        } else if (o < 16384) {
            int g = o - 8192; int iy = g >> 8, nn = g & 255;
            Wh[iy * KW + nn] = (_Float16)s;
        } else {
            z0[o - 16384] = s;
        }
    }
}

// ---------- phase 1: v via MFMA, weighted-sum reduction -> chunk end state S ----------
__global__ __launch_bounds__(256) void k_phase1(
    const float* __restrict__ u, const float* __restrict__ lam,
    const _Float16* __restrict__ Bzh, float* __restrict__ S)
{
    __shared__ __align__(16) _Float16 ut[2][SUBT][32];  // swizzled, double-buffered

    const int b = blockIdx.x >> 6, c = blockIdx.x & 63, tid = threadIdx.x;
    const int w = tid >> 6, lane = tid & 63, m16 = lane & 15, quad = lane >> 4;

    half8_t bfrag[4];
    #pragma unroll
    for (int i = 0; i < 4; ++i)
        bfrag[i] = *(const half8_t*)&Bzh[((4 * w + i) * 16 + m16) * NU + quad * 8];

    float wr[4][4], wt16[4], l32[4], acc[4];
    #pragma unroll
    for (int i = 0; i < 4; ++i) {
        float la = lam[(4 * w + i) * 16 + m16];
        float p2 = la * la, p4 = p2 * p2, p8 = p4 * p4, p16 = p8 * p8;
        float inv1 = 1.0f / la;
        float inv4 = (inv1 * inv1) * (inv1 * inv1);
        float pq = 1.0f;
        if (quad & 1) pq *= inv4;
        if (quad & 2) pq *= inv4 * inv4;
        float w0 = (p16 * p8 * p4 * p2 * la) * pq;      // lam^(31-4q)
        wr[i][0] = w0;
        wr[i][1] = w0 * inv1;
        wr[i][2] = wr[i][1] * inv1;
        wr[i][3] = wr[i][2] * inv1;
        wt16[i] = 1.0f / p16;                            // lam^-16
        l32[i] = p16 * p16;                              // lam^32
        acc[i] = 0.f;
    }

    const float* ug = u + ((size_t)(b * T) + (size_t)c * L) * NU;

    for (int sub = 0; sub < NSUB; ++sub) {
        {   // stage u tile (32t x 32j) f16, swizzled: col' = (col + (t&3)*8) & 31
            float4 uu = *(const float4*)(ug + (size_t)sub * SUBT * NU + tid * 4);
            int tr = tid >> 3, cb = ((tid & 7) * 4 + (tr & 3) * 8) & 31;
            half4_t h; h.x = (_Float16)uu.x; h.y = (_Float16)uu.y;
            h.z = (_Float16)uu.z; h.w = (_Float16)uu.w;
            *(half4_t*)&ut[sub & 1][tr][cb] = h;
        }
        __syncthreads();
        int rot = (m16 & 3) * 8;
        half8_t af0 = *(const half8_t*)&ut[sub & 1][m16][(quad * 8 + rot) & 31];
        half8_t af1 = *(const half8_t*)&ut[sub & 1][16 + m16][(quad * 8 + rot) & 31];
        #pragma unroll
        for (int i = 0; i < 4; ++i) {
            f32x4 z4 = {0.f, 0.f, 0.f, 0.f};
            f32x4 v0 = __builtin_amdgcn_mfma_f32_16x16x32_f16(af0, bfrag[i], z4, 0, 0, 0);
            f32x4 v1 = __builtin_amdgcn_mfma_f32_16x16x32_f16(af1, bfrag[i], z4, 0, 0, 0);
            float s0 = wr[i][0] * v0[0] + wr[i][1] * v0[1] + wr[i][2] * v0[2] + wr[i][3] * v0[3];
            float s1 = wr[i][0] * v1[0] + wr[i][1] * v1[1] + wr[i][2] * v1[2] + wr[i][3] * v1[3];
            acc[i] = fmaf(l32[i], acc[i], fmaf(wt16[i], s1, s0));
        }
    }
    #pragma unroll
    for (int i = 0; i < 4; ++i) {
        acc[i] += __shfl_xor(acc[i], 16);
        acc[i] += __shfl_xor(acc[i], 32);
    }
    float out = quad == 0 ? acc[0] : quad == 1 ? acc[1] : quad == 2 ? acc[2] : acc[3];
    S[(size_t)blockIdx.x * NX + (4 * w + quad) * 16 + m16] = out;
}

// ---------- phase 3: inline prefix -> v-MFMA -> Tri-MFMA scan -> proj MFMA -> y ----------
__global__ __launch_bounds__(256) void k_phase3(
    const float* __restrict__ u, const float* __restrict__ lam,
    const _Float16* __restrict__ Bzh, const _Float16* __restrict__ Wh,
    const float* __restrict__ S, const float* __restrict__ z0,
    float* __restrict__ y)
{
    __shared__ __align__(16) _Float16 ut[2][SUBT][32];  // 4 KB
    __shared__ __align__(16) _Float16 pool[POOLSZ];     // 20.5 KB: V'^T then zt
    __shared__ float pvec[NX];                          // 1 KB

    const int b = blockIdx.x >> 6, c = blockIdx.x & 63, tid = threadIdx.x;
    const int w = tid >> 6, lane = tid & 63, m16 = lane & 15, quad = lane >> 4;
    const int tw = w & 1, yw = w >> 1;                  // proj: t-tile, y-tile

    // ---- inline prefix: pvec[n] = sum_k lamL^k S[b, c-1-k, n] + lamL^c z0[b, n] ----
    {
        float la = lam[tid], lamL = la;
        #pragma unroll
        for (int i = 0; i < 7; ++i) lamL *= lamL;       // lam^128
        const float* Sb = S + (size_t)(b * NC) * NX;
        float pv = 0.f, wgt = 1.f;
        for (int cc = c - 1; cc >= 0; --cc) {           // c==0: skipped
            pv = fmaf(wgt, Sb[(size_t)cc * NX + tid], pv);
            wgt *= lamL;
        }
        pvec[tid] = fmaf(wgt, z0[b * NX + tid], pv);    // wgt == lamL^c
    }

    half8_t bfrag[4];
    #pragma unroll
    for (int i = 0; i < 4; ++i)
        bfrag[i] = *(const half8_t*)&Bzh[((4 * w + i) * 16 + m16) * NU + quad * 8];
    half8_t wfrag[9];
    #pragma unroll
    for (int kk = 0; kk < 9; ++kk)
        wfrag[kk] = *(const half8_t*)&Wh[(yw * 16 + m16) * KW + kk * 32 + quad * 8];
    half8_t triA[2];                                    // Tri[t][s] = (s < t)
    #pragma unroll
    for (int tt = 0; tt < 2; ++tt) {
        #pragma unroll
        for (int j = 0; j < 8; ++j)
            triA[tt][j] = (_Float16)((quad * 8 + j < tt * 16 + m16) ? 1.f : 0.f);
    }

    // per-col lambda powers
    float lamn[4], inv1[4], iq[4], i16p[4], fq[4], f16p[4], l32[4], p[4];
    #pragma unroll
    for (int i = 0; i < 4; ++i) {
        int ni = (4 * w + i) * 16 + m16;
        float la = lam[ni];
        lamn[i] = la;
        float p2 = la * la, p4 = p2 * p2, p8 = p4 * p4, p16 = p8 * p8;
        float iv = 1.0f / la;
        inv1[i] = iv;
        float iv4 = (iv * iv) * (iv * iv);
        float pqi = 1.0f, pqf = 1.0f;
        if (quad & 1) { pqi *= iv4; pqf *= p4; }
        if (quad & 2) { pqi *= iv4 * iv4; pqf *= p8; }
        iq[i] = iv * pqi;                               // lam^-(1+4q)
        fq[i] = pqf;                                    // lam^(4q)
        i16p[i] = 1.0f / p16;
        f16p[i] = p16;
        l32[i] = p16 * p16;
    }
    __syncthreads();                                    // pvec ready
    #pragma unroll
    for (int i = 0; i < 4; ++i)
        p[i] = pvec[(4 * w + i) * 16 + m16];

    const float* ug = u + ((size_t)(b * T) + (size_t)c * L) * NU;
    float* yg = y + ((size_t)(b * T) + (size_t)c * L) * NY;
    const int rot = (m16 & 3) * 8;

    for (int sub = 0; sub < NSUB; ++sub) {
        {   // stage u tile (swizzled, dbuf)
            float4 uu = *(const float4*)(ug + (size_t)sub * SUBT * NU + tid * 4);
            int tr = tid >> 3, cb = ((tid & 7) * 4 + (tr & 3) * 8) & 31;
            half4_t h; h.x = (_Float16)uu.x; h.y = (_Float16)uu.y;
            h.z = (_Float16)uu.z; h.w = (_Float16)uu.w;
            *(half4_t*)&ut[sub & 1][tr][cb] = h;
        }
        __syncthreads();                                 // B1

        // v = u @ Bz^T ; scale V'[s] = lam^-(1+s) v_s ; store V'^T ; partial sums
        half8_t af0 = *(const half8_t*)&ut[sub & 1][m16][(quad * 8 + rot) & 31];
        half8_t af1 = *(const half8_t*)&ut[sub & 1][16 + m16][(quad * 8 + rot) & 31];
        float partial[4];
        #pragma unroll
        for (int i = 0; i < 4; ++i) {
            int ni = (4 * w + i) * 16 + m16;
            f32x4 z4 = {0.f, 0.f, 0.f, 0.f};
            f32x4 v0 = __builtin_amdgcn_mfma_f32_16x16x32_f16(af0, bfrag[i], z4, 0, 0, 0);
            f32x4 v1 = __builtin_amdgcn_mfma_f32_16x16x32_f16(af1, bfrag[i], z4, 0, 0, 0);
            float ps = 0.f;
            float sc = iq[i];                            // lam^-(1+4q+r), r running
            half4_t h0, h1;
            #pragma unroll
            for (int r = 0; r < 4; ++r) {
                float a0 = v0[r] * sc;
                float a1 = v1[r] * (sc * i16p[i]);
                ps += a0 + a1;
                h0[r] = (_Float16)a0;
                h1[r] = (_Float16)a1;
                sc *= inv1[i];
            }
            partial[i] = ps;
            *(half4_t*)&pool[ni * VP + quad * 4] = h0;
            *(half4_t*)&pool[ni * VP + 16 + quad * 4] = h1;
        }
        __syncthreads();                                 // B2

        // Z' = Tri @ V'
        f32x4 zp0[4], zp1[4];
        #pragma unroll
        for (int i = 0; i < 4; ++i) {
            int ni = (4 * w + i) * 16 + m16;
            half8_t bV = *(const half8_t*)&pool[ni * VP + quad * 8];
            f32x4 z4 = {0.f, 0.f, 0.f, 0.f};
            zp0[i] = __builtin_amdgcn_mfma_f32_16x16x32_f16(triA[0], bV, z4, 0, 0, 0);
            zp1[i] = __builtin_amdgcn_mfma_f32_16x16x32_f16(triA[1], bV, z4, 0, 0, 0);
        }
        __syncthreads();                                 // B3 (pool: V'^T -> zt)

        // z_prev[t] = lam^t (p + Z'[t]) ; store zt rows (A layout) as f16
        #pragma unroll
        for (int i = 0; i < 4; ++i) {
            int ni = (4 * w + i) * 16 + m16;
            float f = fq[i];                             // lam^(4q+r), r running
            #pragma unroll
            for (int r = 0; r < 4; ++r) {
                float zv0 = f * (p[i] + zp0[i][r]);
                float zv1 = (f * f16p[i]) * (p[i] + zp1[i][r]);
                pool[(quad * 4 + r) * ZP + ni] = (_Float16)zv0;
                pool[(16 + quad * 4 + r) * ZP + ni] = (_Float16)zv1;
                f *= lamn[i];
            }
        }
        // carry update: p <- lam^32 (p + sum_s lam^-(1+s) v_s)
        #pragma unroll
        for (int i = 0; i < 4; ++i) {
            float ps = partial[i];
            ps += __shfl_xor(ps, 16);
            ps += __shfl_xor(ps, 32);
            p[i] = l32[i] * (p[i] + ps);
        }
        __syncthreads();                                 // B4

        // y = [z_prev | u] @ [Cz | D]^T
        f32x4 acc = {0.f, 0.f, 0.f, 0.f};
        #pragma unroll
        for (int kk = 0; kk < 8; ++kk) {
            half8_t az = *(const half8_t*)&pool[(tw * 16 + m16) * ZP + kk * 32 + quad * 8];
            acc = __builtin_amdgcn_mfma_f32_16x16x32_f16(az, wfrag[kk], acc, 0, 0, 0);
        }
        {
            half8_t au = *(const half8_t*)&ut[sub & 1][tw * 16 + m16][(quad * 8 + rot) & 31];
            acc = __builtin_amdgcn_mfma_f32_16x16x32_f16(au, wfrag[8], acc, 0, 0, 0);
        }
        #pragma unroll
        for (int r = 0; r < 4; ++r)
            yg[(size_t)(sub * SUBT + tw * 16 + quad * 4 + r) * NY + yw * 16 + m16] = acc[r];
    }
}

extern "C" void kernel_launch(void* const* d_in, const int* in_sizes, int n_in,
                              void* d_out, int out_size, void* d_ws, size_t ws_size,
                              hipStream_t stream) {
    (void)in_sizes; (void)n_in; (void)out_size; (void)ws_size;
    const float* x0  = (const float*)d_in[0];
    const float* u   = (const float*)d_in[1];
    const float* Q   = (const float*)d_in[2];
    const float* lam = (const float*)d_in[3];
    const float* Bm  = (const float*)d_in[4];
    const float* C   = (const float*)d_in[5];
    const float* D   = (const float*)d_in[6];
    float* y = (float*)d_out;

    char* ws = (char*)d_ws;
    _Float16* Bzh = (_Float16*)(ws);                    // 16384 B
    _Float16* Wh  = (_Float16*)(ws + 16384);            // 18432 B
    float*    z0  = (float*)(ws + 34816);               // 16384 B
    float*    S   = (float*)(ws + 51200);               // 1 MB

    k_pre   <<<336, 256, 0, stream>>>(x0, Q, Bm, C, D, Bzh, Wh, z0);
    k_phase1<<<BATCH * NC, 256, 0, stream>>>(u, lam, Bzh, S);
    k_phase3<<<BATCH * NC, 256, 0, stream>>>(u, lam, Bzh, Wh, S, z0, y);
}

// Round 6
// 118.551 us; speedup vs baseline: 1.9136x; 1.0957x over previous
//
#include <hip/hip_runtime.h>

typedef _Float16 half4_t __attribute__((ext_vector_type(4)));
typedef _Float16 half8_t __attribute__((ext_vector_type(8)));
typedef float f32x4 __attribute__((ext_vector_type(4)));

constexpr int NX = 256, NU = 32, NY = 32, BATCH = 16, T = 8192;
constexpr int NC = 64, L = 128;       // 64 chunks of 128 steps
constexpr int SUBT = 32, NSUB = L / SUBT;
constexpr int KW = NX + NU;           // 288 projection K: [z | u]
constexpr int ZP = 264;               // zt pitch (halves)

// ---------- pre: Bzh=(Q^T Bm) f16, Wh=[CQ|D] f16, z0=x0 Q f32 ; split-K x4 ----------
__global__ __launch_bounds__(256) void k_pre(
    const float* __restrict__ x0, const float* __restrict__ Q,
    const float* __restrict__ Bm, const float* __restrict__ C,
    const float* __restrict__ D,
    _Float16* __restrict__ Bzh, _Float16* __restrict__ Wh, float* __restrict__ z0)
{
    int o = blockIdx.x * 64 + (threadIdx.x >> 2);
    int p = threadIdx.x & 3;
    if (o >= 20480) {                                   // D copy
        if (p == 0) {
            int g = o - 20480, iy = g >> 5, j = g & 31;
            Wh[iy * KW + NX + j] = (_Float16)D[iy * NU + j];
        }
        return;
    }
    float s = 0.f;
    int k0 = p * 64;
    if (o < 8192) {                                     // Bzh[n][j] = sum_k Q[k][n] Bm[k][j]
        int n = o >> 5, j = o & 31;
        for (int k = k0; k < k0 + 64; ++k) s = fmaf(Q[k * NX + n], Bm[k * NU + j], s);
    } else if (o < 16384) {                             // CQ[iy][nn]
        int g = o - 8192; int iy = g >> 8, nn = g & 255;
        for (int k = k0; k < k0 + 64; ++k) s = fmaf(C[iy * NX + k], Q[k * NX + nn], s);
    } else {                                            // z0[b][nn]
        int g = o - 16384; int b = g >> 8, nn = g & 255;
        for (int k = k0; k < k0 + 64; ++k) s = fmaf(x0[b * NX + k], Q[k * NX + nn], s);
    }
    s += __shfl_xor(s, 1);
    s += __shfl_xor(s, 2);
    if (p == 0) {
        if (o < 8192) {
            Bzh[o] = (_Float16)s;
        } else if (o < 16384) {
            int g = o - 8192; int iy = g >> 8, nn = g & 255;
            Wh[iy * KW + nn] = (_Float16)s;
        } else {
            z0[o - 16384] = s;
        }
    }
}

// ---------- phase 1: v via MFMA, weighted-sum reduction -> chunk end state S ----------
__global__ __launch_bounds__(256) void k_phase1(
    const float* __restrict__ u, const float* __restrict__ lam,
    const _Float16* __restrict__ Bzh, float* __restrict__ S)
{
    __shared__ __align__(16) _Float16 ut[2][SUBT][32];  // swizzled, double-buffered

    const int b = blockIdx.x >> 6, c = blockIdx.x & 63, tid = threadIdx.x;
    const int w = tid >> 6, lane = tid & 63, m16 = lane & 15, quad = lane >> 4;

    half8_t bfrag[4];
    #pragma unroll
    for (int i = 0; i < 4; ++i)
        bfrag[i] = *(const half8_t*)&Bzh[((4 * w + i) * 16 + m16) * NU + quad * 8];

    float wr[4][4], wt16[4], l32[4], acc[4];
    #pragma unroll
    for (int i = 0; i < 4; ++i) {
        float la = lam[(4 * w + i) * 16 + m16];
        float p2 = la * la, p4 = p2 * p2, p8 = p4 * p4, p16 = p8 * p8;
        float inv1 = 1.0f / la;
        float inv4 = (inv1 * inv1) * (inv1 * inv1);
        float pq = 1.0f;
        if (quad & 1) pq *= inv4;
        if (quad & 2) pq *= inv4 * inv4;
        float w0 = (p16 * p8 * p4 * p2 * la) * pq;      // lam^(31-4q)
        wr[i][0] = w0;
        wr[i][1] = w0 * inv1;
        wr[i][2] = wr[i][1] * inv1;
        wr[i][3] = wr[i][2] * inv1;
        wt16[i] = 1.0f / p16;                            // lam^-16
        l32[i] = p16 * p16;                              // lam^32
        acc[i] = 0.f;
    }

    const float* ug = u + ((size_t)(b * T) + (size_t)c * L) * NU;

    for (int sub = 0; sub < NSUB; ++sub) {
        {   // stage u tile (32t x 32j) f16, swizzled: col' = (col + (t&3)*8) & 31
            float4 uu = *(const float4*)(ug + (size_t)sub * SUBT * NU + tid * 4);
            int tr = tid >> 3, cb = ((tid & 7) * 4 + (tr & 3) * 8) & 31;
            half4_t h; h.x = (_Float16)uu.x; h.y = (_Float16)uu.y;
            h.z = (_Float16)uu.z; h.w = (_Float16)uu.w;
            *(half4_t*)&ut[sub & 1][tr][cb] = h;
        }
        __syncthreads();
        int rot = (m16 & 3) * 8;
        half8_t af0 = *(const half8_t*)&ut[sub & 1][m16][(quad * 8 + rot) & 31];
        half8_t af1 = *(const half8_t*)&ut[sub & 1][16 + m16][(quad * 8 + rot) & 31];
        #pragma unroll
        for (int i = 0; i < 4; ++i) {
            f32x4 z4 = {0.f, 0.f, 0.f, 0.f};
            f32x4 v0 = __builtin_amdgcn_mfma_f32_16x16x32_f16(af0, bfrag[i], z4, 0, 0, 0);
            f32x4 v1 = __builtin_amdgcn_mfma_f32_16x16x32_f16(af1, bfrag[i], z4, 0, 0, 0);
            float s0 = wr[i][0] * v0[0] + wr[i][1] * v0[1] + wr[i][2] * v0[2] + wr[i][3] * v0[3];
            float s1 = wr[i][0] * v1[0] + wr[i][1] * v1[1] + wr[i][2] * v1[2] + wr[i][3] * v1[3];
            acc[i] = fmaf(l32[i], acc[i], fmaf(wt16[i], s1, s0));
        }
    }
    #pragma unroll
    for (int i = 0; i < 4; ++i) {
        acc[i] += __shfl_xor(acc[i], 16);
        acc[i] += __shfl_xor(acc[i], 32);
    }
    float out = quad == 0 ? acc[0] : quad == 1 ? acc[1] : quad == 2 ? acc[2] : acc[3];
    S[(size_t)blockIdx.x * NX + (4 * w + quad) * 16 + m16] = out;
}

// ---------- phase 3: parallel prefix -> v-MFMA -> shuffle-scan -> proj MFMA -> y ----------
__global__ __launch_bounds__(256) void k_phase3(
    const float* __restrict__ u, const float* __restrict__ lam,
    const _Float16* __restrict__ Bzh, const _Float16* __restrict__ Wh,
    const float* __restrict__ S, const float* __restrict__ z0,
    float* __restrict__ y)
{
    __shared__ __align__(16) _Float16 ut[2][SUBT][32];  // 4 KB
    __shared__ __align__(16) _Float16 zt[SUBT][ZP];     // 16.5 KB
    __shared__ float pvec[NX];                          // 1 KB

    const int b = blockIdx.x >> 6, c = blockIdx.x & 63, tid = threadIdx.x;
    const int w = tid >> 6, lane = tid & 63, m16 = lane & 15, quad = lane >> 4;
    const int tw = w & 1, yw = w >> 1;                  // proj: t-tile, y-tile

    // ---- prefix: pvec[n] = sum_k lamL^k S[b, c-1-k, n] + lamL^c z0[b, n] ----
    // weights via exp2 (no serial chain); unroll -> pipelined independent loads
    {
        float la = lam[tid];
        float l2L = 128.0f * __log2f(la);               // log2(lam^128)
        const float* Sb = S + (size_t)(b * NC) * NX + tid;
        float pv = 0.f;
        #pragma unroll 8
        for (int k = 0; k < c; ++k) {
            float wgt = exp2f((float)k * l2L);
            pv = fmaf(wgt, Sb[(size_t)(c - 1 - k) * NX], pv);
        }
        pvec[tid] = fmaf(exp2f((float)c * l2L), z0[b * NX + tid], pv);
    }

    half8_t bfrag[4];
    #pragma unroll
    for (int i = 0; i < 4; ++i)
        bfrag[i] = *(const half8_t*)&Bzh[((4 * w + i) * 16 + m16) * NU + quad * 8];
    half8_t wfrag[9];
    #pragma unroll
    for (int kk = 0; kk < 9; ++kk)
        wfrag[kk] = *(const half8_t*)&Wh[(yw * 16 + m16) * KW + kk * 32 + quad * 8];

    // per-col lambda powers
    float lamn[4], inv1[4], iq[4], i16p[4], fq[4], f16p[4], l32[4], p[4];
    #pragma unroll
    for (int i = 0; i < 4; ++i) {
        int ni = (4 * w + i) * 16 + m16;
        float la = lam[ni];
        lamn[i] = la;
        float p2 = la * la, p4 = p2 * p2, p8 = p4 * p4, p16 = p8 * p8;
        float iv = 1.0f / la;
        inv1[i] = iv;
        float iv4 = (iv * iv) * (iv * iv);
        float pqi = 1.0f, pqf = 1.0f;
        if (quad & 1) { pqi *= iv4; pqf *= p4; }
        if (quad & 2) { pqi *= iv4 * iv4; pqf *= p8; }
        iq[i] = iv * pqi;                               // lam^-(1+4q)
        fq[i] = pqf;                                    // lam^(4q)
        i16p[i] = 1.0f / p16;
        f16p[i] = p16;
        l32[i] = p16 * p16;
    }
    __syncthreads();                                    // pvec ready
    #pragma unroll
    for (int i = 0; i < 4; ++i)
        p[i] = pvec[(4 * w + i) * 16 + m16];

    const float* ug = u + ((size_t)(b * T) + (size_t)c * L) * NU;
    float* yg = y + ((size_t)(b * T) + (size_t)c * L) * NY;
    const int rot = (m16 & 3) * 8;

    for (int sub = 0; sub < NSUB; ++sub) {
        {   // stage u tile (swizzled, dbuf)
            float4 uu = *(const float4*)(ug + (size_t)sub * SUBT * NU + tid * 4);
            int tr = tid >> 3, cb = ((tid & 7) * 4 + (tr & 3) * 8) & 31;
            half4_t h; h.x = (_Float16)uu.x; h.y = (_Float16)uu.y;
            h.z = (_Float16)uu.z; h.w = (_Float16)uu.w;
            *(half4_t*)&ut[sub & 1][tr][cb] = h;
        }
        __syncthreads();                                 // B1 (also: prev proj zt-reads done)

        // v = u @ Bz^T ; V'[s] = lam^-(1+s) v_s ; exclusive prefix via shuffles
        half8_t af0 = *(const half8_t*)&ut[sub & 1][m16][(quad * 8 + rot) & 31];
        half8_t af1 = *(const half8_t*)&ut[sub & 1][16 + m16][(quad * 8 + rot) & 31];
        #pragma unroll
        for (int i = 0; i < 4; ++i) {
            int ni = (4 * w + i) * 16 + m16;
            f32x4 z4 = {0.f, 0.f, 0.f, 0.f};
            f32x4 v0 = __builtin_amdgcn_mfma_f32_16x16x32_f16(af0, bfrag[i], z4, 0, 0, 0);
            f32x4 v1 = __builtin_amdgcn_mfma_f32_16x16x32_f16(af1, bfrag[i], z4, 0, 0, 0);
            // prescale: a0[r] = V'[s=quad*4+r], a1[r] = V'[s=16+quad*4+r]
            float a0[4], a1[4];
            float sc = iq[i];
            #pragma unroll
            for (int r = 0; r < 4; ++r) {
                a0[r] = v0[r] * sc;
                a1[r] = v1[r] * (sc * i16p[i]);
                sc *= inv1[i];
            }
            // in-lane exclusive prefixes + lane sums
            float e0[4], e1[4];
            e0[0] = 0.f; e0[1] = a0[0]; e0[2] = e0[1] + a0[1]; e0[3] = e0[2] + a0[2];
            float S40 = e0[3] + a0[3];
            e1[0] = 0.f; e1[1] = a1[0]; e1[2] = e1[1] + a1[1]; e1[3] = e1[2] + a1[2];
            float S41 = e1[3] + a1[3];
            // Hillis-Steele inclusive scan across quads (lanes m16, m16+16, ..)
            float incl0 = S40;
            float t0 = __shfl_up(incl0, 16); if (quad >= 1) incl0 += t0;
            t0 = __shfl_up(incl0, 32);       if (quad >= 2) incl0 += t0;
            float excl0 = incl0 - S40;
            float total0 = __shfl(incl0, 48 + m16);
            float incl1 = S41;
            float t1 = __shfl_up(incl1, 16); if (quad >= 1) incl1 += t1;
            t1 = __shfl_up(incl1, 32);       if (quad >= 2) incl1 += t1;
            float excl1 = incl1 - S41;
            float total1 = __shfl(incl1, 48 + m16);
            // z_prev[t] = lam^t (p + Z'[t]) ; store zt rows (A layout) f16
            float f = fq[i];
            #pragma unroll
            for (int r = 0; r < 4; ++r) {
                float zv0 = f * (p[i] + (excl0 + e0[r]));
                float zv1 = (f * f16p[i]) * (p[i] + (total0 + excl1 + e1[r]));
                zt[quad * 4 + r][ni] = (_Float16)zv0;
                zt[16 + quad * 4 + r][ni] = (_Float16)zv1;
                f *= lamn[i];
            }
            // carry: p <- lam^32 (p + sum of all V')
            p[i] = l32[i] * (p[i] + (total0 + total1));
        }
        __syncthreads();                                 // B2: zt ready

        // y = [z_prev | u] @ [Cz | D]^T
        f32x4 acc = {0.f, 0.f, 0.f, 0.f};
        #pragma unroll
        for (int kk = 0; kk < 8; ++kk) {
            half8_t az = *(const half8_t*)&zt[tw * 16 + m16][kk * 32 + quad * 8];
            acc = __builtin_amdgcn_mfma_f32_16x16x32_f16(az, wfrag[kk], acc, 0, 0, 0);
        }
        {
            half8_t au = *(const half8_t*)&ut[sub & 1][tw * 16 + m16][(quad * 8 + rot) & 31];
            acc = __builtin_amdgcn_mfma_f32_16x16x32_f16(au, wfrag[8], acc, 0, 0, 0);
        }
        #pragma unroll
        for (int r = 0; r < 4; ++r)
            yg[(size_t)(sub * SUBT + tw * 16 + quad * 4 + r) * NY + yw * 16 + m16] = acc[r];
    }
}

extern "C" void kernel_launch(void* const* d_in, const int* in_sizes, int n_in,
                              void* d_out, int out_size, void* d_ws, size_t ws_size,
                              hipStream_t stream) {
    (void)in_sizes; (void)n_in; (void)out_size; (void)ws_size;
    const float* x0  = (const float*)d_in[0];
    const float* u   = (const float*)d_in[1];
    const float* Q   = (const float*)d_in[2];
    const float* lam = (const float*)d_in[3];
    const float* Bm  = (const float*)d_in[4];
    const float* C   = (const float*)d_in[5];
    const float* D   = (const float*)d_in[6];
    float* y = (float*)d_out;

    char* ws = (char*)d_ws;
    _Float16* Bzh = (_Float16*)(ws);                    // 16384 B
    _Float16* Wh  = (_Float16*)(ws + 16384);            // 18432 B
    float*    z0  = (float*)(ws + 34816);               // 16384 B
    float*    S   = (float*)(ws + 51200);               // 1 MB

    k_pre   <<<336, 256, 0, stream>>>(x0, Q, Bm, C, D, Bzh, Wh, z0);
    k_phase1<<<BATCH * NC, 256, 0, stream>>>(u, lam, Bzh, S);
    k_phase3<<<BATCH * NC, 256, 0, stream>>>(u, lam, Bzh, Wh, S, z0, y);
}